// Round 7
// baseline (213.273 us; speedup 1.0000x reference)
//
#include <hip/hip_runtime.h>
#include <hip/hip_bf16.h>

#define BB 16
#define CC 64
#define NN 2048
#define KK 4
#define NPART 2
#define JPER (NN / NPART)
#define NCAND 24
#define TOPT 6

typedef unsigned short u16;
typedef __attribute__((ext_vector_type(4))) float f32x4;
typedef __attribute__((ext_vector_type(16))) float f32x16;
typedef __attribute__((ext_vector_type(8))) short short8;

__device__ __forceinline__ float bf2f(u16 u) {
    unsigned int x = ((unsigned int)u) << 16;
    float f;
    __builtin_memcpy(&f, &x, 4);
    return f;
}
__device__ __forceinline__ u16 f2bf(float f) {
    __hip_bfloat16 h = __float2bfloat16(f);
    u16 u;
    __builtin_memcpy(&u, &h, 2);
    return u;
}
__device__ __forceinline__ unsigned int pk2(float a, float b) {
    return (unsigned int)f2bf(a) | ((unsigned int)f2bf(b) << 16);
}

// K1: transpose x (B,C,N) -> xt (B,N,C), compute xx = sum_c x^2
__global__ __launch_bounds__(256) void k_prep(const float* __restrict__ x,
                                              float* __restrict__ xt,
                                              float* __restrict__ xx) {
    int b = blockIdx.y;
    int n = blockIdx.x * 256 + threadIdx.x;
    const float* xb = x + (size_t)b * CC * NN;
    float v[CC];
    float s = 0.f;
#pragma unroll
    for (int c = 0; c < CC; c++) {
        v[c] = xb[(size_t)c * NN + n];
        s = fmaf(v[c], v[c], s);
    }
    float4* dst = (float4*)(xt + ((size_t)b * NN + n) * CC);
#pragma unroll
    for (int q = 0; q < 16; q++) {
        dst[q] = make_float4(v[4 * q], v[4 * q + 1], v[4 * q + 2], v[4 * q + 3]);
    }
    xx[b * NN + n] = s;
}

// K1b: pack weights to bf16 fragment-linear layout (for 16x16x32 MLP mfma).
__global__ __launch_bounds__(256) void k_wprep(const float* __restrict__ w1,
                                               const float* __restrict__ w2,
                                               const float* __restrict__ w3,
                                               u16* __restrict__ wb1,
                                               u16* __restrict__ wb2,
                                               u16* __restrict__ wb3) {
    int t = blockIdx.x * 256 + threadIdx.x;
    int stride = gridDim.x * 256;
    for (int idx = t; idx < 64 * 128; idx += stride) {  // w1: 64 out x 128 k
        int o = idx >> 7, k = idx & 127;
        int cb = o >> 4, lr = o & 15, ks = k >> 5, g = (k >> 3) & 3, e = k & 7;
        wb1[((cb * 4 + ks) * 64 + g * 16 + lr) * 8 + e] = f2bf(w1[idx]);
    }
    for (int idx = t; idx < 128 * 192; idx += stride) {  // w2: 128 out x 192 k
        int o = idx / 192, k = idx - o * 192;
        int cb = o >> 4, lr = o & 15, ks = k >> 5, g = (k >> 3) & 3, e = k & 7;
        wb2[((cb * 6 + ks) * 64 + g * 16 + lr) * 8 + e] = f2bf(w2[idx]);
    }
    for (int idx = t; idx < 64 * 64; idx += stride) {  // w3: 64 out x 64 k
        int o = idx >> 6, k = idx & 63;
        int cb = o >> 4, lr = o & 15, ks = k >> 5, g = (k >> 3) & 3, e = k & 7;
        wb3[((cb * 2 + ks) * 64 + g * 16 + lr) * 8 + e] = f2bf(w3[idx]);
    }
}

// K2: swapped-operand MFMA KNN. Block: 128 i (4 waves x 32), j-part of 1024.
// D = mfma_32x32x16(A=j_tile, B=i_frag): col(lane&31)=i, row=j -> each lane
// holds 16 j-scores for ONE i in regs. Top-6 per lane half-stream, 24 cand/i.
__global__ __launch_bounds__(256) void k_knn3(const float* __restrict__ xt,
                                              const float* __restrict__ xx,
                                              int* __restrict__ cand) {
    int ib = blockIdx.x;   // 0..15  (128 i-rows each)
    int part = blockIdx.y; // 0..NPART-1
    int b = blockIdx.z;
    int tid = threadIdx.x;
    int i0 = ib * 128;
    int j00 = part * JPER;

    // Bb layout: [buf][sub][oct][row32][8 bf16] -> conflict-free b128 reads
    __shared__ u16 Bb[2 * 2 * 8 * 32 * 8];  // 16 KB
    __shared__ float xxs[JPER];             // 4 KB

    int w = tid >> 6, l = tid & 63;
    int lc = l & 31, lh = l >> 5;
    int hb4 = lh * 4;

    // stage part's xx slice
#pragma unroll
    for (int c = tid; c < JPER; c += 256) xxs[c] = xx[b * NN + j00 + c];

    // i-fragments from global (once): B[k][n]: n=lane&31=i, k=(lane>>5)*8+e
    short8 ifrag[4];
    {
        const float* ip = xt + ((size_t)b * NN + i0 + w * 32 + lc) * CC;
#pragma unroll
        for (int ks = 0; ks < 4; ks++) {
            const float4* fp = (const float4*)(ip + (ks * 2 + lh) * 8);
            float4 a0 = fp[0], a1 = fp[1];
            uint4 u;
            u.x = pk2(a0.x, a0.y); u.y = pk2(a0.z, a0.w);
            u.z = pk2(a1.x, a1.y); u.w = pk2(a1.z, a1.w);
            __builtin_memcpy(&ifrag[ks], &u, 16);
        }
    }

    float v[TOPT];
    int id[TOPT];
#pragma unroll
    for (int s = 0; s < TOPT; s++) {
        v[s] = -3.4e38f;
        id[s] = 0x7fffffff;
    }

    int base_l = lh * 512 + lc * 16;  // byte offset within [oct-pair] region

#define STAGE(rr, bf)                                                              \
    {                                                                              \
        int jb = j00 + (rr) * 64;                                                  \
        for (int c = tid; c < 512; c += 256) {                                     \
            int row = c >> 3, oct = c & 7;                                         \
            const float* sp = xt + ((size_t)b * NN + jb + row) * CC + oct * 8;     \
            float4 a0 = ((const float4*)sp)[0];                                    \
            float4 a1 = ((const float4*)sp)[1];                                    \
            uint4 u;                                                               \
            u.x = pk2(a0.x, a0.y); u.y = pk2(a0.z, a0.w);                          \
            u.z = pk2(a1.x, a1.y); u.w = pk2(a1.z, a1.w);                          \
            int sub = row >> 5, r32 = row & 31;                                    \
            *(uint4*)((char*)Bb + (bf) * 8192 + sub * 4096 + (oct * 32 + r32) * 16) = u; \
        }                                                                          \
    }

    STAGE(0, 0);

    for (int r = 0; r < JPER / 64; r++) {
        __syncthreads();  // buf[r&1] ready; everyone done reading buf[(r+1)&1]
        if (r + 1 < JPER / 64) STAGE(r + 1, (r + 1) & 1);

        const char* bufp = (const char*)Bb + (r & 1) * 8192;
#pragma unroll
        for (int sub = 0; sub < 2; sub++) {
            f32x16 acc;
#pragma unroll
            for (int e = 0; e < 16; e++) acc[e] = 0.f;
#pragma unroll
            for (int ks = 0; ks < 4; ks++) {
                short8 aj = *(const short8*)(bufp + sub * 4096 + ks * 1024 + base_l);
                acc = __builtin_amdgcn_mfma_f32_32x32x16_bf16(aj, ifrag[ks], acc, 0, 0, 0);
            }
            int jl0 = r * 64 + sub * 32;
#pragma unroll
            for (int rg = 0; rg < 16; rg++) {
                int jl = jl0 + (rg & 3) + 8 * (rg >> 2) + hb4;
                float s = fmaf(2.f, acc[rg], -xxs[jl]);
                if (s > v[TOPT - 1]) {
                    float cv = s;
                    int ci = j00 + jl;
#pragma unroll
                    for (int t = 0; t < TOPT; t++) {
                        bool gt = cv > v[t];
                        float nv = gt ? cv : v[t];
                        int ni = gt ? ci : id[t];
                        float ov = gt ? v[t] : cv;
                        int oi = gt ? id[t] : ci;
                        v[t] = nv; id[t] = ni; cv = ov; ci = oi;
                    }
                }
            }
        }
    }
#undef STAGE

    size_t cb = ((size_t)b * NN + i0 + w * 32 + lc) * NCAND + part * 12 + lh * 6;
#pragma unroll
    for (int s = 0; s < TOPT; s++) cand[cb + s] = id[s];
}

// K3: fp64 refine of 24 candidates -> exact top-4 set
__global__ __launch_bounds__(256) void k_knn_merge(const float* __restrict__ xt,
                                                   const int* __restrict__ cand,
                                                   int* __restrict__ nidx) {
    int gid = blockIdx.x * 256 + threadIdx.x;
    int b = gid >> 11;
    int i = gid & (NN - 1);
    const float* xrow = xt + ((size_t)b * NN + i) * CC;
    float xi[CC];
#pragma unroll
    for (int c = 0; c < CC; c++) xi[c] = xrow[c];
    double xxi = 0.0;
#pragma unroll
    for (int c = 0; c < CC; c++) xxi += (double)xi[c] * (double)xi[c];

    double v4[4];
    int id4[4];
#pragma unroll
    for (int s = 0; s < 4; s++) {
        v4[s] = -1e300;
        id4[s] = 0x7fffffff;
    }

    size_t base = (size_t)gid * NCAND;
    for (int cnd = 0; cnd < NCAND; cnd++) {
        int j = cand[base + cnd];
        const float* xj = xt + ((size_t)b * NN + j) * CC;
        double dot = 0.0, sj = 0.0;
#pragma unroll
        for (int c = 0; c < CC; c++) {
            double a = (double)xi[c];
            double bb = (double)xj[c];
            dot += a * bb;
            sj += bb * bb;
        }
        double negd = 2.0 * dot - xxi - sj;
        double cv = negd;
        int ci = j;
#pragma unroll
        for (int s = 0; s < 4; s++) {
            bool take = (cv > v4[s]) || (cv == v4[s] && ci < id4[s]);
            double nv = take ? cv : v4[s];
            int ni = take ? ci : id4[s];
            double ov = take ? v4[s] : cv;
            int oi = take ? id4[s] : ci;
            v4[s] = nv;
            id4[s] = ni;
            cv = ov;
            ci = oi;
        }
    }
#pragma unroll
    for (int s = 0; s < 4; s++) nidx[(size_t)gid * 4 + s] = id4[s];
}

// K4: fused MFMA MLP. Block: 64 items (16 n x 4 k), 4 waves; wave w owns
// item-rows 16w..16w+15. Weights read as pre-packed bf16 fragments (L2-hot).
__global__ __launch_bounds__(256) void k_mlp(const float* __restrict__ xt,
                                             const int* __restrict__ nidx,
                                             const u16* __restrict__ wb1,
                                             const u16* __restrict__ wb2,
                                             const u16* __restrict__ wb3,
                                             const float* __restrict__ b1,
                                             const float* __restrict__ b2,
                                             const float* __restrict__ b3,
                                             float* __restrict__ out) {
    int nch = blockIdx.x;  // 0..127
    int b = blockIdx.y;
    int n0 = nch * 16;
    int tid = threadIdx.x;

    __shared__ u16 Fb[64 * 128];   // raw features bf16, swizzled (16 KB)
    __shared__ u16 E1b[64 * 64];   // relu(e1) (8 KB)
    __shared__ u16 E2b[64 * 128];  // relu(e2) (16 KB)
    __shared__ float Ob[64 * 36];  // e3 k-maxed, padded (9 KB)
    __shared__ int ji[64];

    if (tid < 64) ji[tid] = nidx[((size_t)b * NN + n0) * KK + tid];
    __syncthreads();

    // gather: F[item][0..63]=center, [64..127]=neighbor (swizzled bf16)
    for (int g = tid; g < 64 * 16; g += 256) {
        int it = g >> 4, q = g & 15;
        int half = q >> 3, cq = q & 7;
        int srcn = half ? ji[it] : (n0 + (it >> 2));
        const float* sp = xt + ((size_t)b * NN + srcn) * CC + cq * 8;
        float4 a0 = ((const float4*)sp)[0];
        float4 a1 = ((const float4*)sp)[1];
        uint4 u;
        u.x = pk2(a0.x, a0.y); u.y = pk2(a0.z, a0.w);
        u.z = pk2(a1.x, a1.y); u.w = pk2(a1.z, a1.w);
        int byte = (it * 256 + half * 128 + cq * 16) ^ ((it & 7) << 4);
        *(uint4*)((char*)Fb + byte) = u;
    }
    __syncthreads();

    int w = tid >> 6, l = tid & 63;
    int lr = l & 15, lg = l >> 4;
    int arow = w * 16 + lr;
    int aswz = (arow & 7) << 4;

    // ---- e1: [64 items x 128] x [128 x 64 out] ----
    {
        f32x4 acc[4];
#pragma unroll
        for (int cb = 0; cb < 4; cb++) acc[cb] = (f32x4){0.f, 0.f, 0.f, 0.f};
#pragma unroll
        for (int ks = 0; ks < 4; ks++) {
            int off = (arow * 256 + ks * 64 + lg * 16) ^ aswz;
            short8 a = *(const short8*)((const char*)Fb + off);
#pragma unroll
            for (int cb = 0; cb < 4; cb++) {
                short8 bw = *(const short8*)(wb1 + ((size_t)(cb * 4 + ks) * 64 + l) * 8);
                acc[cb] = __builtin_amdgcn_mfma_f32_16x16x32_bf16(a, bw, acc[cb], 0, 0, 0);
            }
        }
#pragma unroll
        for (int cb = 0; cb < 4; cb++) {
            float bias = b1[cb * 16 + lr];
#pragma unroll
            for (int q = 0; q < 4; q++) {
                int item = w * 16 + lg * 4 + q;
                float vv = fmaxf(acc[cb][q] + bias, 0.f);
                int byte = (item * 128 + (cb * 16 + lr) * 2) ^ ((item & 7) << 4);
                *(u16*)((char*)E1b + byte) = f2bf(vv);
            }
        }
    }
    __syncthreads();

    // ---- e2: [64 x 192] x [192 x 128 out]; k<64 from E1, k>=64 from relu(F) ----
    {
        f32x4 acc[8];
#pragma unroll
        for (int cb = 0; cb < 8; cb++) acc[cb] = (f32x4){0.f, 0.f, 0.f, 0.f};
#pragma unroll
        for (int ks = 0; ks < 6; ks++) {
            short8 a;
            if (ks < 2) {
                int off = (arow * 128 + ks * 64 + lg * 16) ^ aswz;
                a = *(const short8*)((const char*)E1b + off);
            } else {
                int off = (arow * 256 + (ks - 2) * 64 + lg * 16) ^ aswz;
                uint4 u = *(const uint4*)((const char*)Fb + off);
                unsigned int m;
                m = ((u.x >> 15) & 0x10001u) * 0xFFFFu; u.x &= ~m;
                m = ((u.y >> 15) & 0x10001u) * 0xFFFFu; u.y &= ~m;
                m = ((u.z >> 15) & 0x10001u) * 0xFFFFu; u.z &= ~m;
                m = ((u.w >> 15) & 0x10001u) * 0xFFFFu; u.w &= ~m;
                __builtin_memcpy(&a, &u, 16);
            }
#pragma unroll
            for (int cb = 0; cb < 8; cb++) {
                short8 bw = *(const short8*)(wb2 + ((size_t)(cb * 6 + ks) * 64 + l) * 8);
                acc[cb] = __builtin_amdgcn_mfma_f32_16x16x32_bf16(a, bw, acc[cb], 0, 0, 0);
            }
        }
#pragma unroll
        for (int cb = 0; cb < 8; cb++) {
            float bias = b2[cb * 16 + lr];
#pragma unroll
            for (int q = 0; q < 4; q++) {
                int item = w * 16 + lg * 4 + q;
                float vv = fmaxf(acc[cb][q] + bias, 0.f);
                int byte = (item * 256 + (cb * 16 + lr) * 2) ^ ((item & 7) << 4);
                *(u16*)((char*)E2b + byte) = f2bf(vv);
            }
        }
    }
    __syncthreads();

    // ---- e3: for r in {0,1}: [64 x 64] x [64 x 64 out]; k-max in-lane ----
#pragma unroll
    for (int r = 0; r < 2; r++) {
        f32x4 acc[4];
#pragma unroll
        for (int cb = 0; cb < 4; cb++) acc[cb] = (f32x4){0.f, 0.f, 0.f, 0.f};
#pragma unroll
        for (int ks = 0; ks < 2; ks++) {
            int off = (arow * 256 + r * 128 + ks * 64 + lg * 16) ^ aswz;
            short8 a = *(const short8*)((const char*)E2b + off);
#pragma unroll
            for (int cb = 0; cb < 4; cb++) {
                short8 bw = *(const short8*)(wb3 + ((size_t)(cb * 2 + ks) * 64 + l) * 8);
                acc[cb] = __builtin_amdgcn_mfma_f32_16x16x32_bf16(a, bw, acc[cb], 0, 0, 0);
            }
        }
        // regs q=0..3 are exactly the 4 k-neighbors of n_local = w*4 + lg
#pragma unroll
        for (int cb = 0; cb < 4; cb++) {
            float m = fmaxf(fmaxf(acc[cb][0], acc[cb][1]), fmaxf(acc[cb][2], acc[cb][3])) + b3[cb * 16 + lr];
            int o = cb * 16 + lr;
            int nl = w * 4 + lg;
            Ob[o * 36 + nl * 2 + r] = m;
        }
    }
    __syncthreads();

    // coalesced store: thread t -> out channel t>>2, 8 floats
    {
        int o = tid >> 2, q = tid & 3;
        float4 v0 = *(const float4*)&Ob[o * 36 + q * 8];
        float4 v1 = *(const float4*)&Ob[o * 36 + q * 8 + 4];
        float* dst = out + ((size_t)(b * 64 + o)) * 4096 + n0 * 2 + q * 8;
        ((float4*)dst)[0] = v0;
        ((float4*)dst)[1] = v1;
    }
}

extern "C" void kernel_launch(void* const* d_in, const int* in_sizes, int n_in,
                              void* d_out, int out_size, void* d_ws, size_t ws_size,
                              hipStream_t stream) {
    const float* x = (const float*)d_in[0];
    const float* w1 = (const float*)d_in[1];
    const float* b1 = (const float*)d_in[2];
    const float* w2 = (const float*)d_in[3];
    const float* b2 = (const float*)d_in[4];
    const float* w3 = (const float*)d_in[5];
    const float* b3 = (const float*)d_in[6];
    float* out = (float*)d_out;

    // workspace layout
    float* xt = (float*)d_ws;                         // B*N*C fp32 = 8 MB
    float* xx = xt + (size_t)BB * NN * CC;            // B*N
    int* nidx = (int*)(xx + (size_t)BB * NN);         // B*N*K
    int* cand = nidx + (size_t)BB * NN * KK;          // B*N*NCAND
    u16* wb1 = (u16*)(cand + (size_t)BB * NN * NCAND);
    u16* wb2 = wb1 + 64 * 128;
    u16* wb3 = wb2 + 128 * 192;

    k_prep<<<dim3(NN / 256, BB), 256, 0, stream>>>(x, xt, xx);
    k_wprep<<<dim3(32), 256, 0, stream>>>(w1, w2, w3, wb1, wb2, wb3);
    k_knn3<<<dim3(NN / 128, NPART, BB), 256, 0, stream>>>(xt, xx, cand);
    k_knn_merge<<<dim3(BB * NN / 256), 256, 0, stream>>>(xt, cand, nidx);
    k_mlp<<<dim3(NN / 16, BB), 256, 0, stream>>>(xt, nidx, wb1, wb2, wb3, b1, b2, b3, out);
}

// Round 8
// 186.811 us; speedup vs baseline: 1.1417x; 1.1417x over previous
//
#include <hip/hip_runtime.h>
#include <hip/hip_bf16.h>

#define BB 16
#define CC 64
#define NN 2048
#define KK 4
#define NPART 4
#define JPER (NN / NPART)
#define NCAND 32
#define TOPT 4

typedef unsigned short u16;
typedef __attribute__((ext_vector_type(4))) float f32x4;
typedef __attribute__((ext_vector_type(16))) float f32x16;
typedef __attribute__((ext_vector_type(8))) short short8;

__device__ __forceinline__ float bf2f(u16 u) {
    unsigned int x = ((unsigned int)u) << 16;
    float f;
    __builtin_memcpy(&f, &x, 4);
    return f;
}
__device__ __forceinline__ u16 f2bf(float f) {
    __hip_bfloat16 h = __float2bfloat16(f);
    u16 u;
    __builtin_memcpy(&u, &h, 2);
    return u;
}
__device__ __forceinline__ unsigned int pk2(float a, float b) {
    return (unsigned int)f2bf(a) | ((unsigned int)f2bf(b) << 16);
}

// K1: transpose x (B,C,N) -> xt (B,N,C), compute xx = sum_c x^2
__global__ __launch_bounds__(256) void k_prep(const float* __restrict__ x,
                                              float* __restrict__ xt,
                                              float* __restrict__ xx) {
    int b = blockIdx.y;
    int n = blockIdx.x * 256 + threadIdx.x;
    const float* xb = x + (size_t)b * CC * NN;
    float v[CC];
    float s = 0.f;
#pragma unroll
    for (int c = 0; c < CC; c++) {
        v[c] = xb[(size_t)c * NN + n];
        s = fmaf(v[c], v[c], s);
    }
    float4* dst = (float4*)(xt + ((size_t)b * NN + n) * CC);
#pragma unroll
    for (int q = 0; q < 16; q++) {
        dst[q] = make_float4(v[4 * q], v[4 * q + 1], v[4 * q + 2], v[4 * q + 3]);
    }
    xx[b * NN + n] = s;
}

// K1b: pack weights to bf16 fragment-linear layout (for 16x16x32 MLP mfma).
__global__ __launch_bounds__(256) void k_wprep(const float* __restrict__ w1,
                                               const float* __restrict__ w2,
                                               const float* __restrict__ w3,
                                               u16* __restrict__ wb1,
                                               u16* __restrict__ wb2,
                                               u16* __restrict__ wb3) {
    int t = blockIdx.x * 256 + threadIdx.x;
    int stride = gridDim.x * 256;
    for (int idx = t; idx < 64 * 128; idx += stride) {  // w1: 64 out x 128 k
        int o = idx >> 7, k = idx & 127;
        int cb = o >> 4, lr = o & 15, ks = k >> 5, g = (k >> 3) & 3, e = k & 7;
        wb1[((cb * 4 + ks) * 64 + g * 16 + lr) * 8 + e] = f2bf(w1[idx]);
    }
    for (int idx = t; idx < 128 * 192; idx += stride) {  // w2: 128 out x 192 k
        int o = idx / 192, k = idx - o * 192;
        int cb = o >> 4, lr = o & 15, ks = k >> 5, g = (k >> 3) & 3, e = k & 7;
        wb2[((cb * 6 + ks) * 64 + g * 16 + lr) * 8 + e] = f2bf(w2[idx]);
    }
    for (int idx = t; idx < 64 * 64; idx += stride) {  // w3: 64 out x 64 k
        int o = idx >> 6, k = idx & 63;
        int cb = o >> 4, lr = o & 15, ks = k >> 5, g = (k >> 3) & 3, e = k & 7;
        wb3[((cb * 2 + ks) * 64 + g * 16 + lr) * 8 + e] = f2bf(w3[idx]);
    }
}

// K2: swapped-operand MFMA KNN. Block: 128 i (4 waves x 32), j-part of 512.
// D = mfma_32x32x16(A=j_tile, B=i_frag): lane holds 16 j-scores of one i.
// LDS layout slot = r32 ^ oct (bank-conflict-free stores AND reads).
// Dual acc chains for MFMA ILP. Top-4 per lane half-stream -> 32 cand/i.
__global__ __launch_bounds__(256) void k_knn3(const float* __restrict__ xt,
                                              const float* __restrict__ xx,
                                              int* __restrict__ cand) {
    int ib = blockIdx.x;   // 0..15  (128 i-rows each)
    int part = blockIdx.y; // 0..NPART-1
    int b = blockIdx.z;
    int tid = threadIdx.x;
    int i0 = ib * 128;
    int j00 = part * JPER;

    // Bb: [buf][sub][oct][slot=r32^oct][8 bf16]
    __shared__ u16 Bb[2 * 2 * 8 * 32 * 8];  // 16 KB
    __shared__ float xxs[JPER];             // 2 KB

    int w = tid >> 6, l = tid & 63;
    int lc = l & 31, lh = l >> 5;
    int hb4 = lh * 4;

    for (int c = tid; c < JPER; c += 256) xxs[c] = xx[b * NN + j00 + c];

    // i-fragments from global (once): B[k][n]: n=lane&31=i, k=(lane>>5)*8+e
    short8 ifrag[4];
    {
        const float* ip = xt + ((size_t)b * NN + i0 + w * 32 + lc) * CC;
#pragma unroll
        for (int ks = 0; ks < 4; ks++) {
            const float4* fp = (const float4*)(ip + (ks * 2 + lh) * 8);
            float4 a0 = fp[0], a1 = fp[1];
            uint4 u;
            u.x = pk2(a0.x, a0.y); u.y = pk2(a0.z, a0.w);
            u.z = pk2(a1.x, a1.y); u.w = pk2(a1.z, a1.w);
            __builtin_memcpy(&ifrag[ks], &u, 16);
        }
    }

    float v[TOPT];
    int id[TOPT];
#pragma unroll
    for (int s = 0; s < TOPT; s++) {
        v[s] = -3.4e38f;
        id[s] = 0x7fffffff;
    }

#define STAGE(rr, bf)                                                              \
    {                                                                              \
        int jb = j00 + (rr) * 64;                                                  \
        for (int c = tid; c < 512; c += 256) {                                     \
            int row = c >> 3, oct = c & 7;                                         \
            const float* sp = xt + ((size_t)b * NN + jb + row) * CC + oct * 8;     \
            float4 a0 = ((const float4*)sp)[0];                                    \
            float4 a1 = ((const float4*)sp)[1];                                    \
            uint4 u;                                                               \
            u.x = pk2(a0.x, a0.y); u.y = pk2(a0.z, a0.w);                          \
            u.z = pk2(a1.x, a1.y); u.w = pk2(a1.z, a1.w);                          \
            int sub = row >> 5, r32 = row & 31;                                    \
            *(uint4*)((char*)Bb + (bf) * 8192 + sub * 4096 + oct * 512 +           \
                      ((r32 ^ oct) * 16)) = u;                                     \
        }                                                                          \
    }

    STAGE(0, 0);

    for (int r = 0; r < JPER / 64; r++) {
        __syncthreads();  // buf[r&1] ready; prev reads of buf[(r+1)&1] done
        if (r + 1 < JPER / 64) STAGE(r + 1, (r + 1) & 1);

        const char* bufp = (const char*)Bb + (r & 1) * 8192;
        f32x16 acc0, acc1;
#pragma unroll
        for (int e = 0; e < 16; e++) {
            acc0[e] = 0.f;
            acc1[e] = 0.f;
        }
#pragma unroll
        for (int ks = 0; ks < 4; ks++) {
            int o = ks * 2 + lh;
            int boff = o * 512 + ((lc ^ o) * 16);
            short8 a0 = *(const short8*)(bufp + boff);
            short8 a1 = *(const short8*)(bufp + 4096 + boff);
            acc0 = __builtin_amdgcn_mfma_f32_32x32x16_bf16(a0, ifrag[ks], acc0, 0, 0, 0);
            acc1 = __builtin_amdgcn_mfma_f32_32x32x16_bf16(a1, ifrag[ks], acc1, 0, 0, 0);
        }
#pragma unroll
        for (int sub = 0; sub < 2; sub++) {
            const f32x16& acc = sub ? acc1 : acc0;
            int jb2 = r * 64 + sub * 32 + hb4;
#pragma unroll
            for (int rg = 0; rg < 16; rg++) {
                int off = (rg & 3) + 8 * (rg >> 2);  // constexpr under unroll
                float s = fmaf(2.f, acc[rg], -xxs[jb2 + off]);
                if (s > v[TOPT - 1]) {
                    float cv = s;
                    int ci = j00 + jb2 + off;
#pragma unroll
                    for (int t = 0; t < TOPT; t++) {
                        bool gt = cv > v[t];
                        float nv = gt ? cv : v[t];
                        int ni = gt ? ci : id[t];
                        float ov = gt ? v[t] : cv;
                        int oi = gt ? id[t] : ci;
                        v[t] = nv; id[t] = ni; cv = ov; ci = oi;
                    }
                }
            }
        }
    }
#undef STAGE

    size_t cb = ((size_t)b * NN + i0 + w * 32 + lc) * NCAND + part * 8 + lh * TOPT;
#pragma unroll
    for (int s = 0; s < TOPT; s++) cand[cb + s] = id[s];
}

// K3: fp64 refine of 32 candidates -> exact top-4 set
__global__ __launch_bounds__(256) void k_knn_merge(const float* __restrict__ xt,
                                                   const int* __restrict__ cand,
                                                   int* __restrict__ nidx) {
    int gid = blockIdx.x * 256 + threadIdx.x;
    int b = gid >> 11;
    int i = gid & (NN - 1);
    const float* xrow = xt + ((size_t)b * NN + i) * CC;
    float xi[CC];
#pragma unroll
    for (int c = 0; c < CC; c++) xi[c] = xrow[c];
    double xxi = 0.0;
#pragma unroll
    for (int c = 0; c < CC; c++) xxi += (double)xi[c] * (double)xi[c];

    double v4[4];
    int id4[4];
#pragma unroll
    for (int s = 0; s < 4; s++) {
        v4[s] = -1e300;
        id4[s] = 0x7fffffff;
    }

    size_t base = (size_t)gid * NCAND;
    for (int cnd = 0; cnd < NCAND; cnd++) {
        int j = cand[base + cnd];
        const float* xj = xt + ((size_t)b * NN + j) * CC;
        double dot = 0.0, sj = 0.0;
#pragma unroll
        for (int c = 0; c < CC; c++) {
            double a = (double)xi[c];
            double bb = (double)xj[c];
            dot += a * bb;
            sj += bb * bb;
        }
        double negd = 2.0 * dot - xxi - sj;
        double cv = negd;
        int ci = j;
#pragma unroll
        for (int s = 0; s < 4; s++) {
            bool take = (cv > v4[s]) || (cv == v4[s] && ci < id4[s]);
            double nv = take ? cv : v4[s];
            int ni = take ? ci : id4[s];
            double ov = take ? v4[s] : cv;
            int oi = take ? id4[s] : ci;
            v4[s] = nv;
            id4[s] = ni;
            cv = ov;
            ci = oi;
        }
    }
#pragma unroll
    for (int s = 0; s < 4; s++) nidx[(size_t)gid * 4 + s] = id4[s];
}

// K4: fused MFMA MLP. Block: 64 items (16 n x 4 k), 4 waves; wave w owns
// item-rows 16w..16w+15. Weights read as pre-packed bf16 fragments (L2-hot).
__global__ __launch_bounds__(256) void k_mlp(const float* __restrict__ xt,
                                             const int* __restrict__ nidx,
                                             const u16* __restrict__ wb1,
                                             const u16* __restrict__ wb2,
                                             const u16* __restrict__ wb3,
                                             const float* __restrict__ b1,
                                             const float* __restrict__ b2,
                                             const float* __restrict__ b3,
                                             float* __restrict__ out) {
    int nch = blockIdx.x;  // 0..127
    int b = blockIdx.y;
    int n0 = nch * 16;
    int tid = threadIdx.x;

    __shared__ u16 Fb[64 * 128];   // raw features bf16, swizzled (16 KB)
    __shared__ u16 E1b[64 * 64];   // relu(e1) (8 KB)
    __shared__ u16 E2b[64 * 128];  // relu(e2) (16 KB)
    __shared__ float Ob[64 * 36];  // e3 k-maxed, padded (9 KB)
    __shared__ int ji[64];

    if (tid < 64) ji[tid] = nidx[((size_t)b * NN + n0) * KK + tid];
    __syncthreads();

    // gather: F[item][0..63]=center, [64..127]=neighbor (swizzled bf16)
    for (int g = tid; g < 64 * 16; g += 256) {
        int it = g >> 4, q = g & 15;
        int half = q >> 3, cq = q & 7;
        int srcn = half ? ji[it] : (n0 + (it >> 2));
        const float* sp = xt + ((size_t)b * NN + srcn) * CC + cq * 8;
        float4 a0 = ((const float4*)sp)[0];
        float4 a1 = ((const float4*)sp)[1];
        uint4 u;
        u.x = pk2(a0.x, a0.y); u.y = pk2(a0.z, a0.w);
        u.z = pk2(a1.x, a1.y); u.w = pk2(a1.z, a1.w);
        int byte = (it * 256 + half * 128 + cq * 16) ^ ((it & 7) << 4);
        *(uint4*)((char*)Fb + byte) = u;
    }
    __syncthreads();

    int w = tid >> 6, l = tid & 63;
    int lr = l & 15, lg = l >> 4;
    int arow = w * 16 + lr;
    int aswz = (arow & 7) << 4;

    // ---- e1: [64 items x 128] x [128 x 64 out] ----
    {
        f32x4 acc[4];
#pragma unroll
        for (int cb = 0; cb < 4; cb++) acc[cb] = (f32x4){0.f, 0.f, 0.f, 0.f};
#pragma unroll
        for (int ks = 0; ks < 4; ks++) {
            int off = (arow * 256 + ks * 64 + lg * 16) ^ aswz;
            short8 a = *(const short8*)((const char*)Fb + off);
#pragma unroll
            for (int cb = 0; cb < 4; cb++) {
                short8 bw = *(const short8*)(wb1 + ((size_t)(cb * 4 + ks) * 64 + l) * 8);
                acc[cb] = __builtin_amdgcn_mfma_f32_16x16x32_bf16(a, bw, acc[cb], 0, 0, 0);
            }
        }
#pragma unroll
        for (int cb = 0; cb < 4; cb++) {
            float bias = b1[cb * 16 + lr];
#pragma unroll
            for (int q = 0; q < 4; q++) {
                int item = w * 16 + lg * 4 + q;
                float vv = fmaxf(acc[cb][q] + bias, 0.f);
                int byte = (item * 128 + (cb * 16 + lr) * 2) ^ ((item & 7) << 4);
                *(u16*)((char*)E1b + byte) = f2bf(vv);
            }
        }
    }
    __syncthreads();

    // ---- e2: [64 x 192] x [192 x 128 out]; k<64 from E1, k>=64 from relu(F) ----
    {
        f32x4 acc[8];
#pragma unroll
        for (int cb = 0; cb < 8; cb++) acc[cb] = (f32x4){0.f, 0.f, 0.f, 0.f};
#pragma unroll
        for (int ks = 0; ks < 6; ks++) {
            short8 a;
            if (ks < 2) {
                int off = (arow * 128 + ks * 64 + lg * 16) ^ aswz;
                a = *(const short8*)((const char*)E1b + off);
            } else {
                int off = (arow * 256 + (ks - 2) * 64 + lg * 16) ^ aswz;
                uint4 u = *(const uint4*)((const char*)Fb + off);
                unsigned int m;
                m = ((u.x >> 15) & 0x10001u) * 0xFFFFu; u.x &= ~m;
                m = ((u.y >> 15) & 0x10001u) * 0xFFFFu; u.y &= ~m;
                m = ((u.z >> 15) & 0x10001u) * 0xFFFFu; u.z &= ~m;
                m = ((u.w >> 15) & 0x10001u) * 0xFFFFu; u.w &= ~m;
                __builtin_memcpy(&a, &u, 16);
            }
#pragma unroll
            for (int cb = 0; cb < 8; cb++) {
                short8 bw = *(const short8*)(wb2 + ((size_t)(cb * 6 + ks) * 64 + l) * 8);
                acc[cb] = __builtin_amdgcn_mfma_f32_16x16x32_bf16(a, bw, acc[cb], 0, 0, 0);
            }
        }
#pragma unroll
        for (int cb = 0; cb < 8; cb++) {
            float bias = b2[cb * 16 + lr];
#pragma unroll
            for (int q = 0; q < 4; q++) {
                int item = w * 16 + lg * 4 + q;
                float vv = fmaxf(acc[cb][q] + bias, 0.f);
                int byte = (item * 256 + (cb * 16 + lr) * 2) ^ ((item & 7) << 4);
                *(u16*)((char*)E2b + byte) = f2bf(vv);
            }
        }
    }
    __syncthreads();

    // ---- e3: for r in {0,1}: [64 x 64] x [64 x 64 out]; k-max in-lane ----
#pragma unroll
    for (int r = 0; r < 2; r++) {
        f32x4 acc[4];
#pragma unroll
        for (int cb = 0; cb < 4; cb++) acc[cb] = (f32x4){0.f, 0.f, 0.f, 0.f};
#pragma unroll
        for (int ks = 0; ks < 2; ks++) {
            int off = (arow * 256 + r * 128 + ks * 64 + lg * 16) ^ aswz;
            short8 a = *(const short8*)((const char*)E2b + off);
#pragma unroll
            for (int cb = 0; cb < 4; cb++) {
                short8 bw = *(const short8*)(wb3 + ((size_t)(cb * 2 + ks) * 64 + l) * 8);
                acc[cb] = __builtin_amdgcn_mfma_f32_16x16x32_bf16(a, bw, acc[cb], 0, 0, 0);
            }
        }
        // regs q=0..3 are exactly the 4 k-neighbors of n_local = w*4 + lg
#pragma unroll
        for (int cb = 0; cb < 4; cb++) {
            float m = fmaxf(fmaxf(acc[cb][0], acc[cb][1]), fmaxf(acc[cb][2], acc[cb][3])) + b3[cb * 16 + lr];
            int o = cb * 16 + lr;
            int nl = w * 4 + lg;
            Ob[o * 36 + nl * 2 + r] = m;
        }
    }
    __syncthreads();

    // coalesced store: thread t -> out channel t>>2, 8 floats
    {
        int o = tid >> 2, q = tid & 3;
        float4 v0 = *(const float4*)&Ob[o * 36 + q * 8];
        float4 v1 = *(const float4*)&Ob[o * 36 + q * 8 + 4];
        float* dst = out + ((size_t)(b * 64 + o)) * 4096 + n0 * 2 + q * 8;
        ((float4*)dst)[0] = v0;
        ((float4*)dst)[1] = v1;
    }
}

extern "C" void kernel_launch(void* const* d_in, const int* in_sizes, int n_in,
                              void* d_out, int out_size, void* d_ws, size_t ws_size,
                              hipStream_t stream) {
    const float* x = (const float*)d_in[0];
    const float* w1 = (const float*)d_in[1];
    const float* b1 = (const float*)d_in[2];
    const float* w2 = (const float*)d_in[3];
    const float* b2 = (const float*)d_in[4];
    const float* w3 = (const float*)d_in[5];
    const float* b3 = (const float*)d_in[6];
    float* out = (float*)d_out;

    // workspace layout
    float* xt = (float*)d_ws;                         // B*N*C fp32 = 8 MB
    float* xx = xt + (size_t)BB * NN * CC;            // B*N
    int* nidx = (int*)(xx + (size_t)BB * NN);         // B*N*K
    int* cand = nidx + (size_t)BB * NN * KK;          // B*N*NCAND
    u16* wb1 = (u16*)(cand + (size_t)BB * NN * NCAND);
    u16* wb2 = wb1 + 64 * 128;
    u16* wb3 = wb2 + 128 * 192;

    k_prep<<<dim3(NN / 256, BB), 256, 0, stream>>>(x, xt, xx);
    k_wprep<<<dim3(32), 256, 0, stream>>>(w1, w2, w3, wb1, wb2, wb3);
    k_knn3<<<dim3(NN / 128, NPART, BB), 256, 0, stream>>>(xt, xx, cand);
    k_knn_merge<<<dim3(BB * NN / 256), 256, 0, stream>>>(xt, cand, nidx);
    k_mlp<<<dim3(NN / 16, BB), 256, 0, stream>>>(xt, nidx, wb1, wb2, wb3, b1, b2, b3, out);
}

// Round 10
// 154.834 us; speedup vs baseline: 1.3774x; 1.2065x over previous
//
#include <hip/hip_runtime.h>
#include <hip/hip_bf16.h>

#define BB 16
#define CC 64
#define NN 2048
#define KK 4
#define NPART 4
#define JPER (NN / NPART)
#define NCAND 32
#define TOPT 4

typedef unsigned short u16;
typedef __attribute__((ext_vector_type(4))) float f32x4;
typedef __attribute__((ext_vector_type(16))) float f32x16;
typedef __attribute__((ext_vector_type(8))) short short8;

__device__ __forceinline__ float bf2f(u16 u) {
    unsigned int x = ((unsigned int)u) << 16;
    float f;
    __builtin_memcpy(&f, &x, 4);
    return f;
}
__device__ __forceinline__ u16 f2bf(float f) {
    __hip_bfloat16 h = __float2bfloat16(f);
    u16 u;
    __builtin_memcpy(&u, &h, 2);
    return u;
}
__device__ __forceinline__ unsigned int pk2(float a, float b) {
    return (unsigned int)f2bf(a) | ((unsigned int)f2bf(b) << 16);
}

// K1: transpose x (B,C,N) -> xt (B,N,C), compute xx = sum_c x^2
__global__ __launch_bounds__(256) void k_prep(const float* __restrict__ x,
                                              float* __restrict__ xt,
                                              float* __restrict__ xx) {
    int b = blockIdx.y;
    int n = blockIdx.x * 256 + threadIdx.x;
    const float* xb = x + (size_t)b * CC * NN;
    float v[CC];
    float s = 0.f;
#pragma unroll
    for (int c = 0; c < CC; c++) {
        v[c] = xb[(size_t)c * NN + n];
        s = fmaf(v[c], v[c], s);
    }
    float4* dst = (float4*)(xt + ((size_t)b * NN + n) * CC);
#pragma unroll
    for (int q = 0; q < 16; q++) {
        dst[q] = make_float4(v[4 * q], v[4 * q + 1], v[4 * q + 2], v[4 * q + 3]);
    }
    xx[b * NN + n] = s;
}

// K1b: pack weights to bf16 fragment-linear layout (for 16x16x32 MLP mfma).
__global__ __launch_bounds__(256) void k_wprep(const float* __restrict__ w1,
                                               const float* __restrict__ w2,
                                               const float* __restrict__ w3,
                                               u16* __restrict__ wb1,
                                               u16* __restrict__ wb2,
                                               u16* __restrict__ wb3) {
    int t = blockIdx.x * 256 + threadIdx.x;
    int stride = gridDim.x * 256;
    for (int idx = t; idx < 64 * 128; idx += stride) {  // w1: 64 out x 128 k
        int o = idx >> 7, k = idx & 127;
        int cb = o >> 4, lr = o & 15, ks = k >> 5, g = (k >> 3) & 3, e = k & 7;
        wb1[((cb * 4 + ks) * 64 + g * 16 + lr) * 8 + e] = f2bf(w1[idx]);
    }
    for (int idx = t; idx < 128 * 192; idx += stride) {  // w2: 128 out x 192 k
        int o = idx / 192, k = idx - o * 192;
        int cb = o >> 4, lr = o & 15, ks = k >> 5, g = (k >> 3) & 3, e = k & 7;
        wb2[((cb * 6 + ks) * 64 + g * 16 + lr) * 8 + e] = f2bf(w2[idx]);
    }
    for (int idx = t; idx < 64 * 64; idx += stride) {  // w3: 64 out x 64 k
        int o = idx >> 6, k = idx & 63;
        int cb = o >> 4, lr = o & 15, ks = k >> 5, g = (k >> 3) & 3, e = k & 7;
        wb3[((cb * 2 + ks) * 64 + g * 16 + lr) * 8 + e] = f2bf(w3[idx]);
    }
}

// K2: swapped-operand MFMA KNN. Block: 128 i (4 waves x 32), j-part of 512.
// D = mfma_32x32x16(A=j_tile, B=i_frag): lane holds 16 j-scores of one i.
// LDS layout slot = r32 ^ oct (bank-conflict-free stores AND reads).
// Dual acc chains for MFMA ILP. Top-4 per lane half-stream -> 32 cand/i.
__global__ __launch_bounds__(256) void k_knn3(const float* __restrict__ xt,
                                              const float* __restrict__ xx,
                                              int* __restrict__ cand) {
    int ib = blockIdx.x;   // 0..15  (128 i-rows each)
    int part = blockIdx.y; // 0..NPART-1
    int b = blockIdx.z;
    int tid = threadIdx.x;
    int i0 = ib * 128;
    int j00 = part * JPER;

    // Bb: [buf][sub][oct][slot=r32^oct][8 bf16]
    __shared__ u16 Bb[2 * 2 * 8 * 32 * 8];  // 16 KB
    __shared__ float xxs[JPER];             // 2 KB

    int w = tid >> 6, l = tid & 63;
    int lc = l & 31, lh = l >> 5;
    int hb4 = lh * 4;

    for (int c = tid; c < JPER; c += 256) xxs[c] = xx[b * NN + j00 + c];

    // i-fragments from global (once): B[k][n]: n=lane&31=i, k=(lane>>5)*8+e
    short8 ifrag[4];
    {
        const float* ip = xt + ((size_t)b * NN + i0 + w * 32 + lc) * CC;
#pragma unroll
        for (int ks = 0; ks < 4; ks++) {
            const float4* fp = (const float4*)(ip + (ks * 2 + lh) * 8);
            float4 a0 = fp[0], a1 = fp[1];
            uint4 u;
            u.x = pk2(a0.x, a0.y); u.y = pk2(a0.z, a0.w);
            u.z = pk2(a1.x, a1.y); u.w = pk2(a1.z, a1.w);
            __builtin_memcpy(&ifrag[ks], &u, 16);
        }
    }

    float v[TOPT];
    int id[TOPT];
#pragma unroll
    for (int s = 0; s < TOPT; s++) {
        v[s] = -3.4e38f;
        id[s] = 0x7fffffff;
    }

#define STAGE(rr, bf)                                                              \
    {                                                                              \
        int jb = j00 + (rr) * 64;                                                  \
        for (int c = tid; c < 512; c += 256) {                                     \
            int row = c >> 3, oct = c & 7;                                         \
            const float* sp = xt + ((size_t)b * NN + jb + row) * CC + oct * 8;     \
            float4 a0 = ((const float4*)sp)[0];                                    \
            float4 a1 = ((const float4*)sp)[1];                                    \
            uint4 u;                                                               \
            u.x = pk2(a0.x, a0.y); u.y = pk2(a0.z, a0.w);                          \
            u.z = pk2(a1.x, a1.y); u.w = pk2(a1.z, a1.w);                          \
            int sub = row >> 5, r32 = row & 31;                                    \
            *(uint4*)((char*)Bb + (bf) * 8192 + sub * 4096 + oct * 512 +           \
                      ((r32 ^ oct) * 16)) = u;                                     \
        }                                                                          \
    }

    STAGE(0, 0);

    for (int r = 0; r < JPER / 64; r++) {
        __syncthreads();  // buf[r&1] ready; prev reads of buf[(r+1)&1] done
        if (r + 1 < JPER / 64) STAGE(r + 1, (r + 1) & 1);

        const char* bufp = (const char*)Bb + (r & 1) * 8192;
        f32x16 acc0, acc1;
#pragma unroll
        for (int e = 0; e < 16; e++) {
            acc0[e] = 0.f;
            acc1[e] = 0.f;
        }
#pragma unroll
        for (int ks = 0; ks < 4; ks++) {
            int o = ks * 2 + lh;
            int boff = o * 512 + ((lc ^ o) * 16);
            short8 a0 = *(const short8*)(bufp + boff);
            short8 a1 = *(const short8*)(bufp + 4096 + boff);
            acc0 = __builtin_amdgcn_mfma_f32_32x32x16_bf16(a0, ifrag[ks], acc0, 0, 0, 0);
            acc1 = __builtin_amdgcn_mfma_f32_32x32x16_bf16(a1, ifrag[ks], acc1, 0, 0, 0);
        }
#pragma unroll
        for (int sub = 0; sub < 2; sub++) {
            const f32x16& acc = sub ? acc1 : acc0;
            int jb2 = r * 64 + sub * 32 + hb4;
#pragma unroll
            for (int rg = 0; rg < 16; rg++) {
                int off = (rg & 3) + 8 * (rg >> 2);  // constexpr under unroll
                float s = fmaf(2.f, acc[rg], -xxs[jb2 + off]);
                if (s > v[TOPT - 1]) {
                    float cv = s;
                    int ci = j00 + jb2 + off;
#pragma unroll
                    for (int t = 0; t < TOPT; t++) {
                        bool gt = cv > v[t];
                        float nv = gt ? cv : v[t];
                        int ni = gt ? ci : id[t];
                        float ov = gt ? v[t] : cv;
                        int oi = gt ? id[t] : ci;
                        v[t] = nv; id[t] = ni; cv = ov; ci = oi;
                    }
                }
            }
        }
    }
#undef STAGE

    size_t cb = ((size_t)b * NN + i0 + w * 32 + lc) * NCAND + part * 8 + lh * TOPT;
#pragma unroll
    for (int s = 0; s < TOPT; s++) cand[cb + s] = id[s];
}

// K3: fp64 refine, 8 threads/point, 32 points/block (1024 blocks).
// Each thread computes 4 of the 32 candidate distances; LDS merge; one
// thread/point does the 32->top-4 insertion (tie: smaller idx).
__global__ __launch_bounds__(256) void k_knn_merge(const float* __restrict__ xt,
                                                   const int* __restrict__ cand,
                                                   int* __restrict__ nidx) {
    __shared__ double sv[32 * 33];  // [cand][point], stride 33 (conflict-free)
    __shared__ int si[32 * 33];

    int tid = threadIdx.x;
    int pl = tid >> 3;   // local point 0..31
    int sub = tid & 7;   // candidate group 0..7
    int gp = blockIdx.x * 32 + pl;
    int b = gp >> 11;
    int i = gp & (NN - 1);

    const float* xrow = xt + ((size_t)b * NN + i) * CC;
    float xi[CC];
#pragma unroll
    for (int q = 0; q < 16; q++) {
        float4 t = ((const float4*)xrow)[q];
        xi[4 * q] = t.x; xi[4 * q + 1] = t.y; xi[4 * q + 2] = t.z; xi[4 * q + 3] = t.w;
    }
    double xxi = 0.0;
#pragma unroll
    for (int c = 0; c < CC; c++) xxi += (double)xi[c] * (double)xi[c];

    size_t base = (size_t)gp * NCAND + sub * 4;
#pragma unroll
    for (int cc = 0; cc < 4; cc++) {
        int j = cand[base + cc];
        const float* xj = xt + ((size_t)b * NN + j) * CC;
        double dot = 0.0, sj = 0.0;
#pragma unroll
        for (int q = 0; q < 16; q++) {
            float4 t = ((const float4*)xj)[q];
            double b0 = (double)t.x, b1 = (double)t.y, b2v = (double)t.z, b3v = (double)t.w;
            dot += (double)xi[4 * q] * b0 + (double)xi[4 * q + 1] * b1 +
                   (double)xi[4 * q + 2] * b2v + (double)xi[4 * q + 3] * b3v;
            sj += b0 * b0 + b1 * b1 + b2v * b2v + b3v * b3v;
        }
        int c = sub * 4 + cc;
        sv[c * 33 + pl] = 2.0 * dot - xxi - sj;
        si[c * 33 + pl] = j;
    }
    __syncthreads();

    if (tid < 32) {
        int p = tid;
        double v4[4];
        int id4[4];
#pragma unroll
        for (int s = 0; s < 4; s++) {
            v4[s] = -1e300;
            id4[s] = 0x7fffffff;
        }
        for (int c = 0; c < NCAND; c++) {
            double cv = sv[c * 33 + p];
            int ci = si[c * 33 + p];
#pragma unroll
            for (int s = 0; s < 4; s++) {
                bool take = (cv > v4[s]) || (cv == v4[s] && ci < id4[s]);
                double nv = take ? cv : v4[s];
                int ni = take ? ci : id4[s];
                double ov = take ? v4[s] : cv;
                int oi = take ? id4[s] : ci;
                v4[s] = nv;
                id4[s] = ni;
                cv = ov;
                ci = oi;
            }
        }
        size_t gp2 = (size_t)blockIdx.x * 32 + p;
#pragma unroll
        for (int s = 0; s < 4; s++) nidx[gp2 * 4 + s] = id4[s];
    }
}

// K4: fused MFMA MLP. Block: 64 items (16 n x 4 k), 4 waves; wave w owns
// item-rows 16w..16w+15. Weights read as pre-packed bf16 fragments (L2-hot).
__global__ __launch_bounds__(256) void k_mlp(const float* __restrict__ xt,
                                             const int* __restrict__ nidx,
                                             const u16* __restrict__ wb1,
                                             const u16* __restrict__ wb2,
                                             const u16* __restrict__ wb3,
                                             const float* __restrict__ b1,
                                             const float* __restrict__ b2,
                                             const float* __restrict__ b3,
                                             float* __restrict__ out) {
    int nch = blockIdx.x;  // 0..127
    int b = blockIdx.y;
    int n0 = nch * 16;
    int tid = threadIdx.x;

    __shared__ u16 Fb[64 * 128];   // raw features bf16, swizzled (16 KB)
    __shared__ u16 E1b[64 * 64];   // relu(e1) (8 KB)
    __shared__ u16 E2b[64 * 128];  // relu(e2) (16 KB)
    __shared__ float Ob[64 * 36];  // e3 k-maxed, padded (9 KB)
    __shared__ int ji[64];

    if (tid < 64) ji[tid] = nidx[((size_t)b * NN + n0) * KK + tid];
    __syncthreads();

    // gather: F[item][0..63]=center, [64..127]=neighbor (swizzled bf16)
    for (int g = tid; g < 64 * 16; g += 256) {
        int it = g >> 4, q = g & 15;
        int half = q >> 3, cq = q & 7;
        int srcn = half ? ji[it] : (n0 + (it >> 2));
        const float* sp = xt + ((size_t)b * NN + srcn) * CC + cq * 8;
        float4 a0 = ((const float4*)sp)[0];
        float4 a1 = ((const float4*)sp)[1];
        uint4 u;
        u.x = pk2(a0.x, a0.y); u.y = pk2(a0.z, a0.w);
        u.z = pk2(a1.x, a1.y); u.w = pk2(a1.z, a1.w);
        int byte = (it * 256 + half * 128 + cq * 16) ^ ((it & 7) << 4);
        *(uint4*)((char*)Fb + byte) = u;
    }
    __syncthreads();

    int w = tid >> 6, l = tid & 63;
    int lr = l & 15, lg = l >> 4;
    int arow = w * 16 + lr;
    int aswz = (arow & 7) << 4;

    // ---- e1: [64 items x 128] x [128 x 64 out] ----
    {
        f32x4 acc[4];
#pragma unroll
        for (int cb = 0; cb < 4; cb++) acc[cb] = (f32x4){0.f, 0.f, 0.f, 0.f};
#pragma unroll
        for (int ks = 0; ks < 4; ks++) {
            int off = (arow * 256 + ks * 64 + lg * 16) ^ aswz;
            short8 a = *(const short8*)((const char*)Fb + off);
#pragma unroll
            for (int cb = 0; cb < 4; cb++) {
                short8 bw = *(const short8*)(wb1 + ((size_t)(cb * 4 + ks) * 64 + l) * 8);
                acc[cb] = __builtin_amdgcn_mfma_f32_16x16x32_bf16(a, bw, acc[cb], 0, 0, 0);
            }
        }
#pragma unroll
        for (int cb = 0; cb < 4; cb++) {
            float bias = b1[cb * 16 + lr];
#pragma unroll
            for (int q = 0; q < 4; q++) {
                int item = w * 16 + lg * 4 + q;
                float vv = fmaxf(acc[cb][q] + bias, 0.f);
                int byte = (item * 128 + (cb * 16 + lr) * 2) ^ ((item & 7) << 4);
                *(u16*)((char*)E1b + byte) = f2bf(vv);
            }
        }
    }
    __syncthreads();

    // ---- e2: [64 x 192] x [192 x 128 out]; k<64 from E1, k>=64 from relu(F) ----
    {
        f32x4 acc[8];
#pragma unroll
        for (int cb = 0; cb < 8; cb++) acc[cb] = (f32x4){0.f, 0.f, 0.f, 0.f};
#pragma unroll
        for (int ks = 0; ks < 6; ks++) {
            short8 a;
            if (ks < 2) {
                int off = (arow * 128 + ks * 64 + lg * 16) ^ aswz;
                a = *(const short8*)((const char*)E1b + off);
            } else {
                int off = (arow * 256 + (ks - 2) * 64 + lg * 16) ^ aswz;
                uint4 u = *(const uint4*)((const char*)Fb + off);
                unsigned int m;
                m = ((u.x >> 15) & 0x10001u) * 0xFFFFu; u.x &= ~m;
                m = ((u.y >> 15) & 0x10001u) * 0xFFFFu; u.y &= ~m;
                m = ((u.z >> 15) & 0x10001u) * 0xFFFFu; u.z &= ~m;
                m = ((u.w >> 15) & 0x10001u) * 0xFFFFu; u.w &= ~m;
                __builtin_memcpy(&a, &u, 16);
            }
#pragma unroll
            for (int cb = 0; cb < 8; cb++) {
                short8 bw = *(const short8*)(wb2 + ((size_t)(cb * 6 + ks) * 64 + l) * 8);
                acc[cb] = __builtin_amdgcn_mfma_f32_16x16x32_bf16(a, bw, acc[cb], 0, 0, 0);
            }
        }
#pragma unroll
        for (int cb = 0; cb < 8; cb++) {
            float bias = b2[cb * 16 + lr];
#pragma unroll
            for (int q = 0; q < 4; q++) {
                int item = w * 16 + lg * 4 + q;
                float vv = fmaxf(acc[cb][q] + bias, 0.f);
                int byte = (item * 256 + (cb * 16 + lr) * 2) ^ ((item & 7) << 4);
                *(u16*)((char*)E2b + byte) = f2bf(vv);
            }
        }
    }
    __syncthreads();

    // ---- e3: for r in {0,1}: [64 x 64] x [64 x 64 out]; k-max in-lane ----
#pragma unroll
    for (int r = 0; r < 2; r++) {
        f32x4 acc[4];
#pragma unroll
        for (int cb = 0; cb < 4; cb++) acc[cb] = (f32x4){0.f, 0.f, 0.f, 0.f};
#pragma unroll
        for (int ks = 0; ks < 2; ks++) {
            int off = (arow * 256 + r * 128 + ks * 64 + lg * 16) ^ aswz;
            short8 a = *(const short8*)((const char*)E2b + off);
#pragma unroll
            for (int cb = 0; cb < 4; cb++) {
                short8 bw = *(const short8*)(wb3 + ((size_t)(cb * 2 + ks) * 64 + l) * 8);
                acc[cb] = __builtin_amdgcn_mfma_f32_16x16x32_bf16(a, bw, acc[cb], 0, 0, 0);
            }
        }
        // regs q=0..3 are exactly the 4 k-neighbors of n_local = w*4 + lg
#pragma unroll
        for (int cb = 0; cb < 4; cb++) {
            float m = fmaxf(fmaxf(acc[cb][0], acc[cb][1]), fmaxf(acc[cb][2], acc[cb][3])) + b3[cb * 16 + lr];
            int o = cb * 16 + lr;
            int nl = w * 4 + lg;
            Ob[o * 36 + nl * 2 + r] = m;
        }
    }
    __syncthreads();

    // coalesced store: thread t -> out channel t>>2, 8 floats
    {
        int o = tid >> 2, q = tid & 3;
        float4 v0 = *(const float4*)&Ob[o * 36 + q * 8];
        float4 v1 = *(const float4*)&Ob[o * 36 + q * 8 + 4];
        float* dst = out + ((size_t)(b * 64 + o)) * 4096 + n0 * 2 + q * 8;
        ((float4*)dst)[0] = v0;
        ((float4*)dst)[1] = v1;
    }
}

extern "C" void kernel_launch(void* const* d_in, const int* in_sizes, int n_in,
                              void* d_out, int out_size, void* d_ws, size_t ws_size,
                              hipStream_t stream) {
    const float* x = (const float*)d_in[0];
    const float* w1 = (const float*)d_in[1];
    const float* b1 = (const float*)d_in[2];
    const float* w2 = (const float*)d_in[3];
    const float* b2 = (const float*)d_in[4];
    const float* w3 = (const float*)d_in[5];
    const float* b3 = (const float*)d_in[6];
    float* out = (float*)d_out;

    // workspace layout
    float* xt = (float*)d_ws;                         // B*N*C fp32 = 8 MB
    float* xx = xt + (size_t)BB * NN * CC;            // B*N
    int* nidx = (int*)(xx + (size_t)BB * NN);         // B*N*K
    int* cand = nidx + (size_t)BB * NN * KK;          // B*N*NCAND
    u16* wb1 = (u16*)(cand + (size_t)BB * NN * NCAND);
    u16* wb2 = wb1 + 64 * 128;
    u16* wb3 = wb2 + 128 * 192;

    k_prep<<<dim3(NN / 256, BB), 256, 0, stream>>>(x, xt, xx);
    k_wprep<<<dim3(32), 256, 0, stream>>>(w1, w2, w3, wb1, wb2, wb3);
    k_knn3<<<dim3(NN / 128, NPART, BB), 256, 0, stream>>>(xt, xx, cand);
    k_knn_merge<<<dim3(BB * NN / 32), 256, 0, stream>>>(xt, cand, nidx);
    k_mlp<<<dim3(NN / 16, BB), 256, 0, stream>>>(xt, nidx, wb1, wb2, wb3, b1, b2, b3, out);
}

// Round 11
// 147.768 us; speedup vs baseline: 1.4433x; 1.0478x over previous
//
#include <hip/hip_runtime.h>
#include <hip/hip_bf16.h>

#define BB 16
#define CC 64
#define NN 2048
#define KK 4
#define NPART 4
#define JPER (NN / NPART)
#define NCAND 32
#define TOPT 4
#define RSTRIDE 80  // bf16 per packed row: 64 coords + xx_hi + xx_lo + 14 zeros

typedef unsigned short u16;
typedef __attribute__((ext_vector_type(4))) float f32x4;
typedef __attribute__((ext_vector_type(16))) float f32x16;
typedef __attribute__((ext_vector_type(8))) short short8;

__device__ __forceinline__ float bf2f(u16 u) {
    unsigned int x = ((unsigned int)u) << 16;
    float f;
    __builtin_memcpy(&f, &x, 4);
    return f;
}
__device__ __forceinline__ u16 f2bf(float f) {
    __hip_bfloat16 h = __float2bfloat16(f);
    u16 u;
    __builtin_memcpy(&u, &h, 2);
    return u;
}
__device__ __forceinline__ unsigned int pk2(float a, float b) {
    return (unsigned int)f2bf(a) | ((unsigned int)f2bf(b) << 16);
}

// K1: transpose x (B,C,N) -> xt (B,N,C) fp32 (for fp64 refine) and
// xpk (B,N,80) bf16: [0..63]=x, [64]=xx_hi, [65]=xx_lo, [66..79]=0.
__global__ __launch_bounds__(256) void k_prep(const float* __restrict__ x,
                                              float* __restrict__ xt,
                                              u16* __restrict__ xpk) {
    int b = blockIdx.y;
    int n = blockIdx.x * 256 + threadIdx.x;
    const float* xb = x + (size_t)b * CC * NN;
    float v[CC];
    float s = 0.f;
#pragma unroll
    for (int c = 0; c < CC; c++) {
        v[c] = xb[(size_t)c * NN + n];
        s = fmaf(v[c], v[c], s);
    }
    float4* dst = (float4*)(xt + ((size_t)b * NN + n) * CC);
#pragma unroll
    for (int q = 0; q < 16; q++) {
        dst[q] = make_float4(v[4 * q], v[4 * q + 1], v[4 * q + 2], v[4 * q + 3]);
    }
    u16* dp = xpk + ((size_t)b * NN + n) * RSTRIDE;
#pragma unroll
    for (int q = 0; q < 8; q++) {
        uint4 u;
        u.x = pk2(v[8 * q], v[8 * q + 1]);
        u.y = pk2(v[8 * q + 2], v[8 * q + 3]);
        u.z = pk2(v[8 * q + 4], v[8 * q + 5]);
        u.w = pk2(v[8 * q + 6], v[8 * q + 7]);
        *(uint4*)(dp + q * 8) = u;
    }
    u16 hi = f2bf(s);
    u16 lo = f2bf(s - bf2f(hi));
    uint4 u8;
    u8.x = (unsigned int)hi | ((unsigned int)lo << 16);
    u8.y = 0; u8.z = 0; u8.w = 0;
    *(uint4*)(dp + 64) = u8;
    uint4 z = {0, 0, 0, 0};
    *(uint4*)(dp + 72) = z;
}

// K1b: pack weights to bf16 fragment-linear layout (for 16x16x32 MLP mfma).
__global__ __launch_bounds__(256) void k_wprep(const float* __restrict__ w1,
                                               const float* __restrict__ w2,
                                               const float* __restrict__ w3,
                                               u16* __restrict__ wb1,
                                               u16* __restrict__ wb2,
                                               u16* __restrict__ wb3) {
    int t = blockIdx.x * 256 + threadIdx.x;
    int stride = gridDim.x * 256;
    for (int idx = t; idx < 64 * 128; idx += stride) {  // w1: 64 out x 128 k
        int o = idx >> 7, k = idx & 127;
        int cb = o >> 4, lr = o & 15, ks = k >> 5, g = (k >> 3) & 3, e = k & 7;
        wb1[((cb * 4 + ks) * 64 + g * 16 + lr) * 8 + e] = f2bf(w1[idx]);
    }
    for (int idx = t; idx < 128 * 192; idx += stride) {  // w2: 128 out x 192 k
        int o = idx / 192, k = idx - o * 192;
        int cb = o >> 4, lr = o & 15, ks = k >> 5, g = (k >> 3) & 3, e = k & 7;
        wb2[((cb * 6 + ks) * 64 + g * 16 + lr) * 8 + e] = f2bf(w2[idx]);
    }
    for (int idx = t; idx < 64 * 64; idx += stride) {  // w3: 64 out x 64 k
        int o = idx >> 6, k = idx & 63;
        int cb = o >> 4, lr = o & 15, ks = k >> 5, g = (k >> 3) & 3, e = k & 7;
        wb3[((cb * 2 + ks) * 64 + g * 16 + lr) * 8 + e] = f2bf(w3[idx]);
    }
}

// K2: swapped-operand MFMA KNN, K=80 (xx folded into MFMA via {xx_hi,xx_lo}
// x {-0.5,-0.5}). acc = dot - xx_j/2: scan is a bare compare. All data staged
// as pre-converted bf16 (uint4 copies). slot = r32^(c&7) -> conflict-free.
__global__ __launch_bounds__(256) void k_knn3(const u16* __restrict__ xpk,
                                              u16* __restrict__ cand) {
    int ib = blockIdx.x;   // 0..15  (128 i-rows each)
    int part = blockIdx.y; // 0..NPART-1
    int b = blockIdx.z;
    int tid = threadIdx.x;
    int i0 = ib * 128;
    int j00 = part * JPER;

    // Bb: [buf][sub][chunk 0..9][slot=r32^(c&7)][16B]
    __shared__ u16 Bb[2 * 2 * 10 * 32 * 8];  // 20 KB

    int w = tid >> 6, l = tid & 63;
    int lc = l & 31, lh = l >> 5;
    int hb4 = lh * 4;

    // i-fragments: B[k][n]: n=lane&31=i, k=(lane>>5)*8+e. Slice 4 = const.
    short8 ifrag[5];
    {
        const u16* ip = xpk + ((size_t)b * NN + i0 + w * 32 + lc) * RSTRIDE + lh * 8;
#pragma unroll
        for (int ks = 0; ks < 4; ks++) ifrag[ks] = *(const short8*)(ip + ks * 16);
        short8 f4 = {0, 0, 0, 0, 0, 0, 0, 0};
        if (lh == 0) {
            f4[0] = (short)0xBF00;  // bf16(-0.5)
            f4[1] = (short)0xBF00;
        }
        ifrag[4] = f4;
    }

    float v[TOPT];
    int id[TOPT];
#pragma unroll
    for (int s = 0; s < TOPT; s++) {
        v[s] = -3.4e38f;
        id[s] = 0x7fffffff;
    }

#define STAGE(rr, bf)                                                              \
    {                                                                              \
        int jb = j00 + (rr) * 64;                                                  \
        for (int g = tid; g < 640; g += 256) {                                     \
            int rw = g / 10, c = g - rw * 10;                                      \
            uint4 u = *(const uint4*)(xpk + ((size_t)b * NN + jb + rw) * RSTRIDE + \
                                      c * 8);                                      \
            int sub = rw >> 5, r32 = rw & 31;                                      \
            *(uint4*)((char*)Bb + (bf) * 10240 + sub * 5120 + c * 512 +            \
                      ((r32 ^ (c & 7)) * 16)) = u;                                 \
        }                                                                          \
    }

    STAGE(0, 0);

    for (int r = 0; r < JPER / 64; r++) {
        __syncthreads();  // buf[r&1] ready; prev reads of buf[(r+1)&1] done
        if (r + 1 < JPER / 64) STAGE(r + 1, (r + 1) & 1);

        const char* bufp = (const char*)Bb + (r & 1) * 10240;
        f32x16 acc0, acc1;
#pragma unroll
        for (int e = 0; e < 16; e++) {
            acc0[e] = 0.f;
            acc1[e] = 0.f;
        }
#pragma unroll
        for (int ks = 0; ks < 5; ks++) {
            int c = ks * 2 + lh;
            int boff = c * 512 + ((lc ^ (c & 7)) * 16);
            short8 a0 = *(const short8*)(bufp + boff);
            short8 a1 = *(const short8*)(bufp + 5120 + boff);
            acc0 = __builtin_amdgcn_mfma_f32_32x32x16_bf16(a0, ifrag[ks], acc0, 0, 0, 0);
            acc1 = __builtin_amdgcn_mfma_f32_32x32x16_bf16(a1, ifrag[ks], acc1, 0, 0, 0);
        }
#pragma unroll
        for (int sub = 0; sub < 2; sub++) {
            const f32x16& acc = sub ? acc1 : acc0;
            int jb2 = r * 64 + sub * 32 + hb4;
#pragma unroll
            for (int rg = 0; rg < 16; rg++) {
                int off = (rg & 3) + 8 * (rg >> 2);  // constexpr under unroll
                float s = acc[rg];                   // = dot - xx_j/2 (monotone in score)
                if (s > v[TOPT - 1]) {
                    float cv = s;
                    int ci = j00 + jb2 + off;
#pragma unroll
                    for (int t = 0; t < TOPT; t++) {
                        bool gt = cv > v[t];
                        float nv = gt ? cv : v[t];
                        int ni = gt ? ci : id[t];
                        float ov = gt ? v[t] : cv;
                        int oi = gt ? id[t] : ci;
                        v[t] = nv; id[t] = ni; cv = ov; ci = oi;
                    }
                }
            }
        }
    }
#undef STAGE

    size_t cb = ((size_t)b * NN + i0 + w * 32 + lc) * NCAND + part * 8 + lh * TOPT;
#pragma unroll
    for (int s = 0; s < TOPT; s++) cand[cb + s] = (u16)id[s];
}

// K3: fp64 refine, 8 threads/point, 32 points/block (1024 blocks).
__global__ __launch_bounds__(256) void k_knn_merge(const float* __restrict__ xt,
                                                   const u16* __restrict__ cand,
                                                   int* __restrict__ nidx) {
    __shared__ double sv[32 * 33];  // [cand][point], stride 33 (conflict-free)
    __shared__ int si[32 * 33];

    int tid = threadIdx.x;
    int pl = tid >> 3;   // local point 0..31
    int sub = tid & 7;   // candidate group 0..7
    int gp = blockIdx.x * 32 + pl;
    int b = gp >> 11;
    int i = gp & (NN - 1);

    const float* xrow = xt + ((size_t)b * NN + i) * CC;
    float xi[CC];
#pragma unroll
    for (int q = 0; q < 16; q++) {
        float4 t = ((const float4*)xrow)[q];
        xi[4 * q] = t.x; xi[4 * q + 1] = t.y; xi[4 * q + 2] = t.z; xi[4 * q + 3] = t.w;
    }
    double xxi = 0.0;
#pragma unroll
    for (int c = 0; c < CC; c++) xxi += (double)xi[c] * (double)xi[c];

    size_t base = (size_t)gp * NCAND + sub * 4;
#pragma unroll
    for (int cc = 0; cc < 4; cc++) {
        int j = cand[base + cc];
        const float* xj = xt + ((size_t)b * NN + j) * CC;
        double dot = 0.0, sj = 0.0;
#pragma unroll
        for (int q = 0; q < 16; q++) {
            float4 t = ((const float4*)xj)[q];
            double b0 = (double)t.x, b1 = (double)t.y, b2v = (double)t.z, b3v = (double)t.w;
            dot += (double)xi[4 * q] * b0 + (double)xi[4 * q + 1] * b1 +
                   (double)xi[4 * q + 2] * b2v + (double)xi[4 * q + 3] * b3v;
            sj += b0 * b0 + b1 * b1 + b2v * b2v + b3v * b3v;
        }
        int c = sub * 4 + cc;
        sv[c * 33 + pl] = 2.0 * dot - xxi - sj;
        si[c * 33 + pl] = j;
    }
    __syncthreads();

    if (tid < 32) {
        int p = tid;
        double v4[4];
        int id4[4];
#pragma unroll
        for (int s = 0; s < 4; s++) {
            v4[s] = -1e300;
            id4[s] = 0x7fffffff;
        }
        for (int c = 0; c < NCAND; c++) {
            double cv = sv[c * 33 + p];
            int ci = si[c * 33 + p];
#pragma unroll
            for (int s = 0; s < 4; s++) {
                bool take = (cv > v4[s]) || (cv == v4[s] && ci < id4[s]);
                double nv = take ? cv : v4[s];
                int ni = take ? ci : id4[s];
                double ov = take ? v4[s] : cv;
                int oi = take ? id4[s] : ci;
                v4[s] = nv;
                id4[s] = ni;
                cv = ov;
                ci = oi;
            }
        }
        size_t gp2 = (size_t)blockIdx.x * 32 + p;
#pragma unroll
        for (int s = 0; s < 4; s++) nidx[gp2 * 4 + s] = id4[s];
    }
}

// K4: fused MFMA MLP. Gather now copies pre-packed bf16 rows (no cvt).
__global__ __launch_bounds__(256) void k_mlp(const u16* __restrict__ xpk,
                                             const int* __restrict__ nidx,
                                             const u16* __restrict__ wb1,
                                             const u16* __restrict__ wb2,
                                             const u16* __restrict__ wb3,
                                             const float* __restrict__ b1,
                                             const float* __restrict__ b2,
                                             const float* __restrict__ b3,
                                             float* __restrict__ out) {
    int nch = blockIdx.x;  // 0..127
    int b = blockIdx.y;
    int n0 = nch * 16;
    int tid = threadIdx.x;

    __shared__ u16 Fb[64 * 128];   // raw features bf16, swizzled (16 KB)
    __shared__ u16 E1b[64 * 64];   // relu(e1) (8 KB)
    __shared__ u16 E2b[64 * 128];  // relu(e2) (16 KB)
    __shared__ float Ob[64 * 36];  // e3 k-maxed, padded (9 KB)
    __shared__ int ji[64];

    if (tid < 64) ji[tid] = nidx[((size_t)b * NN + n0) * KK + tid];
    __syncthreads();

    // gather: F[item][0..63]=center, [64..127]=neighbor (swizzled bf16 copy)
    for (int g = tid; g < 64 * 16; g += 256) {
        int it = g >> 4, q = g & 15;
        int half = q >> 3, cq = q & 7;
        int srcn = half ? ji[it] : (n0 + (it >> 2));
        uint4 u = *(const uint4*)(xpk + ((size_t)b * NN + srcn) * RSTRIDE + cq * 8);
        int byte = (it * 256 + half * 128 + cq * 16) ^ ((it & 7) << 4);
        *(uint4*)((char*)Fb + byte) = u;
    }
    __syncthreads();

    int w = tid >> 6, l = tid & 63;
    int lr = l & 15, lg = l >> 4;
    int arow = w * 16 + lr;
    int aswz = (arow & 7) << 4;

    // ---- e1: [64 items x 128] x [128 x 64 out] ----
    {
        f32x4 acc[4];
#pragma unroll
        for (int cb = 0; cb < 4; cb++) acc[cb] = (f32x4){0.f, 0.f, 0.f, 0.f};
#pragma unroll
        for (int ks = 0; ks < 4; ks++) {
            int off = (arow * 256 + ks * 64 + lg * 16) ^ aswz;
            short8 a = *(const short8*)((const char*)Fb + off);
#pragma unroll
            for (int cb = 0; cb < 4; cb++) {
                short8 bw = *(const short8*)(wb1 + ((size_t)(cb * 4 + ks) * 64 + l) * 8);
                acc[cb] = __builtin_amdgcn_mfma_f32_16x16x32_bf16(a, bw, acc[cb], 0, 0, 0);
            }
        }
#pragma unroll
        for (int cb = 0; cb < 4; cb++) {
            float bias = b1[cb * 16 + lr];
#pragma unroll
            for (int q = 0; q < 4; q++) {
                int item = w * 16 + lg * 4 + q;
                float vv = fmaxf(acc[cb][q] + bias, 0.f);
                int byte = (item * 128 + (cb * 16 + lr) * 2) ^ ((item & 7) << 4);
                *(u16*)((char*)E1b + byte) = f2bf(vv);
            }
        }
    }
    __syncthreads();

    // ---- e2: [64 x 192] x [192 x 128 out]; k<64 from E1, k>=64 from relu(F) ----
    {
        f32x4 acc[8];
#pragma unroll
        for (int cb = 0; cb < 8; cb++) acc[cb] = (f32x4){0.f, 0.f, 0.f, 0.f};
#pragma unroll
        for (int ks = 0; ks < 6; ks++) {
            short8 a;
            if (ks < 2) {
                int off = (arow * 128 + ks * 64 + lg * 16) ^ aswz;
                a = *(const short8*)((const char*)E1b + off);
            } else {
                int off = (arow * 256 + (ks - 2) * 64 + lg * 16) ^ aswz;
                uint4 u = *(const uint4*)((const char*)Fb + off);
                unsigned int m;
                m = ((u.x >> 15) & 0x10001u) * 0xFFFFu; u.x &= ~m;
                m = ((u.y >> 15) & 0x10001u) * 0xFFFFu; u.y &= ~m;
                m = ((u.z >> 15) & 0x10001u) * 0xFFFFu; u.z &= ~m;
                m = ((u.w >> 15) & 0x10001u) * 0xFFFFu; u.w &= ~m;
                __builtin_memcpy(&a, &u, 16);
            }
#pragma unroll
            for (int cb = 0; cb < 8; cb++) {
                short8 bw = *(const short8*)(wb2 + ((size_t)(cb * 6 + ks) * 64 + l) * 8);
                acc[cb] = __builtin_amdgcn_mfma_f32_16x16x32_bf16(a, bw, acc[cb], 0, 0, 0);
            }
        }
#pragma unroll
        for (int cb = 0; cb < 8; cb++) {
            float bias = b2[cb * 16 + lr];
#pragma unroll
            for (int q = 0; q < 4; q++) {
                int item = w * 16 + lg * 4 + q;
                float vv = fmaxf(acc[cb][q] + bias, 0.f);
                int byte = (item * 256 + (cb * 16 + lr) * 2) ^ ((item & 7) << 4);
                *(u16*)((char*)E2b + byte) = f2bf(vv);
            }
        }
    }
    __syncthreads();

    // ---- e3: for r in {0,1}: [64 x 64] x [64 x 64 out]; k-max in-lane ----
#pragma unroll
    for (int r = 0; r < 2; r++) {
        f32x4 acc[4];
#pragma unroll
        for (int cb = 0; cb < 4; cb++) acc[cb] = (f32x4){0.f, 0.f, 0.f, 0.f};
#pragma unroll
        for (int ks = 0; ks < 2; ks++) {
            int off = (arow * 256 + r * 128 + ks * 64 + lg * 16) ^ aswz;
            short8 a = *(const short8*)((const char*)E2b + off);
#pragma unroll
            for (int cb = 0; cb < 4; cb++) {
                short8 bw = *(const short8*)(wb3 + ((size_t)(cb * 2 + ks) * 64 + l) * 8);
                acc[cb] = __builtin_amdgcn_mfma_f32_16x16x32_bf16(a, bw, acc[cb], 0, 0, 0);
            }
        }
        // regs q=0..3 are exactly the 4 k-neighbors of n_local = w*4 + lg
#pragma unroll
        for (int cb = 0; cb < 4; cb++) {
            float m = fmaxf(fmaxf(acc[cb][0], acc[cb][1]), fmaxf(acc[cb][2], acc[cb][3])) + b3[cb * 16 + lr];
            int o = cb * 16 + lr;
            int nl = w * 4 + lg;
            Ob[o * 36 + nl * 2 + r] = m;
        }
    }
    __syncthreads();

    // coalesced store: thread t -> out channel t>>2, 8 floats
    {
        int o = tid >> 2, q = tid & 3;
        float4 v0 = *(const float4*)&Ob[o * 36 + q * 8];
        float4 v1 = *(const float4*)&Ob[o * 36 + q * 8 + 4];
        float* dst = out + ((size_t)(b * 64 + o)) * 4096 + n0 * 2 + q * 8;
        ((float4*)dst)[0] = v0;
        ((float4*)dst)[1] = v1;
    }
}

extern "C" void kernel_launch(void* const* d_in, const int* in_sizes, int n_in,
                              void* d_out, int out_size, void* d_ws, size_t ws_size,
                              hipStream_t stream) {
    const float* x = (const float*)d_in[0];
    const float* w1 = (const float*)d_in[1];
    const float* b1 = (const float*)d_in[2];
    const float* w2 = (const float*)d_in[3];
    const float* b2 = (const float*)d_in[4];
    const float* w3 = (const float*)d_in[5];
    const float* b3 = (const float*)d_in[6];
    float* out = (float*)d_out;

    // workspace layout (~16.3 MB)
    float* xt = (float*)d_ws;                          // B*N*C fp32 = 8 MB
    u16* xpk = (u16*)(xt + (size_t)BB * NN * CC);      // B*N*80 bf16 = 5.24 MB
    int* nidx = (int*)(xpk + (size_t)BB * NN * RSTRIDE);  // B*N*K = 0.5 MB
    u16* cand = (u16*)(nidx + (size_t)BB * NN * KK);   // B*N*NCAND u16 = 2 MB
    u16* wb1 = cand + (size_t)BB * NN * NCAND;
    u16* wb2 = wb1 + 64 * 128;
    u16* wb3 = wb2 + 128 * 192;

    k_prep<<<dim3(NN / 256, BB), 256, 0, stream>>>(x, xt, xpk);
    k_wprep<<<dim3(32), 256, 0, stream>>>(w1, w2, w3, wb1, wb2, wb3);
    k_knn3<<<dim3(NN / 128, NPART, BB), 256, 0, stream>>>(xpk, cand);
    k_knn_merge<<<dim3(BB * NN / 32), 256, 0, stream>>>(xt, cand, nidx);
    k_mlp<<<dim3(NN / 16, BB), 256, 0, stream>>>(xpk, nidx, wb1, wb2, wb3, b1, b2, b3, out);
}